// Round 1
// baseline (7119.125 us; speedup 1.0000x reference)
//
#include <hip/hip_runtime.h>
#include <math.h>

typedef __attribute__((ext_vector_type(8))) short short8;
typedef __attribute__((ext_vector_type(4))) float f32x4;
typedef unsigned short ushort_t;
typedef unsigned int uint32;

// ---------------- ws layout (float units) ----------------
#define WS_E      0        // e[4096]
#define WS_SCORES 4096     // scores[4096]
#define WS_ATT    8192     // att[4096]
#define WS_HID    12288    // hid[1024]
#define WS_HBUF   16384    // u32 hbuf[2 dir][2 parity][512]

// ---------------- d_out layout (float units from base) ----------------
// lin: [0..1024) ; energy region E0 = base+1024 (16,777,216 floats)
// Scratch packed INSIDE energy region (overwritten by k_energy at the end):
#define ENERGY_OFF   1024
#define XP_OFF       0          // bf16 xp[2][4096][1536] = 6,291,456 floats
#define OUTPUTS_OFF  6291456    // float outputs[4096][1024] = 4,194,304 floats
#define XBF_OFF      10485760   // bf16 x[4096][512]   = 1,048,576 floats
#define WIH_OFF      11534336   // bf16 w_ih[3072][512]= 786,432 floats
#define WHH_OFF      12320768   // bf16 w_hh[2][1536][512] = 786,432 floats

__device__ __forceinline__ ushort_t f2bf(float f) {
  uint32 x = __float_as_uint(f);
  return (ushort_t)((x + 0x7fffu + ((x >> 16) & 1u)) >> 16);
}
__device__ __forceinline__ float bf2f(ushort_t u) {
  return __uint_as_float(((uint32)u) << 16);
}

// ============ K1: e[t], x_bf, weight bf16 conversion ============
__global__ __launch_bounds__(256) void k_prep(
    const float* __restrict__ query, const float* __restrict__ input,
    const float* __restrict__ fc_w, const float* __restrict__ fc_b,
    const float* __restrict__ w_ih_f, const float* __restrict__ w_ih_b,
    const float* __restrict__ w_hh_f, const float* __restrict__ w_hh_b,
    float* __restrict__ ws, float* __restrict__ outbase)
{
  int bid = blockIdx.x, tid = threadIdx.x;
  ushort_t* xbf   = (ushort_t*)(outbase + ENERGY_OFF + XBF_OFF);
  ushort_t* wihbf = (ushort_t*)(outbase + ENERGY_OFF + WIH_OFF);
  ushort_t* whhbf = (ushort_t*)(outbase + ENERGY_OFF + WHH_OFF);

  if (bid < 512) {
    int lane = tid & 63, wv = tid >> 6;
    float bconst = fc_b[0];
    const float4* w4 = (const float4*)fc_w;
    float4 b0 = w4[lane*2], b1 = w4[lane*2+1];
    for (int it = 0; it < 2; ++it) {
      int t = bid*8 + it*4 + wv;
      const float4* q4 = (const float4*)(query + (size_t)t*512);
      float4 a0 = q4[lane*2], a1 = q4[lane*2+1];
      float p = a0.x*b0.x + a0.y*b0.y + a0.z*b0.z + a0.w*b0.w
              + a1.x*b1.x + a1.y*b1.y + a1.z*b1.z + a1.w*b1.w;
      #pragma unroll
      for (int m = 1; m < 64; m <<= 1) p += __shfl_xor(p, m, 64);
      float e = p + bconst;
      if (lane == 0) ws[WS_E + t] = e;
      const float4* in4 = (const float4*)(input + (size_t)t*512);
      float4 x0 = in4[lane*2], x1 = in4[lane*2+1];
      short8 o;
      o[0]=(short)f2bf(e*x0.x); o[1]=(short)f2bf(e*x0.y);
      o[2]=(short)f2bf(e*x0.z); o[3]=(short)f2bf(e*x0.w);
      o[4]=(short)f2bf(e*x1.x); o[5]=(short)f2bf(e*x1.y);
      o[6]=(short)f2bf(e*x1.z); o[7]=(short)f2bf(e*x1.w);
      *(short8*)(xbf + (size_t)t*512 + lane*8) = o;
    }
  } else {
    // weight conversion: 3,145,728 elements total, 2048 per block
    size_t gid = (size_t)(bid - 512)*2048 + (size_t)tid*8;
    const float* src; ushort_t* dst; size_t doff, soff;
    if (gid < 786432)        { src = w_ih_f; dst = wihbf; doff = gid;          soff = gid; }
    else if (gid < 1572864)  { src = w_ih_b; dst = wihbf; doff = gid;          soff = gid - 786432; }
    else if (gid < 2359296)  { src = w_hh_f; dst = whhbf; doff = gid - 1572864; soff = gid - 1572864; }
    else                     { src = w_hh_b; dst = whhbf; doff = gid - 1572864; soff = gid - 2359296; }
    float4 v0 = *(const float4*)(src + soff);
    float4 v1 = *(const float4*)(src + soff + 4);
    short8 o;
    o[0]=(short)f2bf(v0.x); o[1]=(short)f2bf(v0.y); o[2]=(short)f2bf(v0.z); o[3]=(short)f2bf(v0.w);
    o[4]=(short)f2bf(v1.x); o[5]=(short)f2bf(v1.y); o[6]=(short)f2bf(v1.z); o[7]=(short)f2bf(v1.w);
    *(short8*)(dst + doff) = o;
  }
}

// ============ K2: xp GEMM  M=4096(t) x N=3072(j stacked f,b) x K=512 ============
__global__ __launch_bounds__(256) void k_xp_gemm(
    const float* __restrict__ b_ih_f, const float* __restrict__ b_ih_b,
    float* __restrict__ outbase)
{
  const ushort_t* xbf   = (const ushort_t*)(outbase + ENERGY_OFF + XBF_OFF);
  const ushort_t* wihbf = (const ushort_t*)(outbase + ENERGY_OFF + WIH_OFF);
  ushort_t* xpbf = (ushort_t*)(outbase + ENERGY_OFF + XP_OFF);

  int m0 = blockIdx.x * 64, n0 = blockIdx.y * 64;
  bool rev = (n0 >= 1536);
  __shared__ ushort_t As[64*40];  // stride 40 shorts (80B) to spread banks
  __shared__ ushort_t Bs[64*40];
  int tid = threadIdx.x;
  int lane = tid & 63, wv = tid >> 6, l15 = lane & 15, quad = lane >> 4;
  int mw = (wv & 1)*32, nw = (wv >> 1)*32;
  f32x4 acc[2][2] = {};
  int lr = tid >> 2, lc = (tid & 3)*8;
  int t_eff = rev ? (4095 - (m0 + lr)) : (m0 + lr);
  const short8* asrc = (const short8*)(xbf + (size_t)t_eff*512 + lc);
  const short8* bsrc = (const short8*)(wihbf + (size_t)(n0 + lr)*512 + lc);

  for (int ks = 0; ks < 16; ++ks) {
    short8 av = asrc[ks*4];
    short8 bv = bsrc[ks*4];
    __syncthreads();
    *(short8*)(As + lr*40 + lc) = av;
    *(short8*)(Bs + lr*40 + lc) = bv;
    __syncthreads();
    short8 bf0 = *(const short8*)(Bs + (nw + l15)*40 + quad*8);
    short8 bf1 = *(const short8*)(Bs + (nw + 16 + l15)*40 + quad*8);
    #pragma unroll
    for (int mi = 0; mi < 2; ++mi) {
      short8 af = *(const short8*)(As + (mw + mi*16 + l15)*40 + quad*8);
      acc[mi][0] = __builtin_amdgcn_mfma_f32_16x16x32_bf16(af, bf0, acc[mi][0], 0, 0, 0);
      acc[mi][1] = __builtin_amdgcn_mfma_f32_16x16x32_bf16(af, bf1, acc[mi][1], 0, 0, 0);
    }
  }
  #pragma unroll
  for (int mi = 0; mi < 2; ++mi) {
    #pragma unroll
    for (int ni = 0; ni < 2; ++ni) {
      int j = n0 + nw + ni*16 + l15;
      int d2 = (j >= 1536) ? 1 : 0;
      int jj = j - d2*1536;
      float bias = d2 ? b_ih_b[jj] : b_ih_f[jj];
      int trow_base = m0 + mw + mi*16 + quad*4;
      #pragma unroll
      for (int r = 0; r < 4; ++r) {
        xpbf[((size_t)(d2*4096 + trow_base + r))*1536 + jj] = f2bf(acc[mi][ni][r] + bias);
      }
    }
  }
}

// ============ K3: persistent bidirectional GRU scan ============
// 64 WGs: d = blk>>5 (0=fwd,1=bwd), g = blk&31, each owns h[i], i in [g*16, g*16+16)
__global__ __launch_bounds__(256) void k_gru(
    const float* __restrict__ b_hh_f, const float* __restrict__ b_hh_b,
    float* __restrict__ ws, float* __restrict__ outbase)
{
  const ushort_t* xpbf  = (const ushort_t*)(outbase + ENERGY_OFF + XP_OFF);
  const ushort_t* whhbf = (const ushort_t*)(outbase + ENERGY_OFF + WHH_OFF);
  float* outputs = outbase + ENERGY_OFF + OUTPUTS_OFF;
  uint32* hbuf = (uint32*)(ws + WS_HBUF);

  int tid = threadIdx.x;
  int d = blockIdx.x >> 5, g = blockIdx.x & 31;
  int I0 = g*16;
  int lane = tid & 63, wv = tid >> 6, l15 = lane & 15, quad = lane >> 4;

  __shared__ ushort_t h_bf[512];
  __shared__ float hp_lds[48];
  __shared__ float bhh_lds[48];
  __shared__ ushort_t xpq[48];

  // Preload W_hh A-fragments into VGPRs (waves 0..2; wave w = gate w tile).
  short8 wfrag[16];
  if (wv < 3) {
    const ushort_t* wrow = whhbf + ((size_t)(d*1536 + wv*512 + I0 + l15))*512 + quad*8;
    #pragma unroll
    for (int kc = 0; kc < 16; ++kc) wfrag[kc] = *(const short8*)(wrow + kc*32);
  }
  if (tid < 48) {
    const float* bhh = d ? b_hh_b : b_hh_f;
    bhh_lds[tid] = bhh[(tid >> 4)*512 + I0 + (tid & 15)];
  }
  h_bf[tid] = 0; h_bf[tid + 256] = 0;

  const ushort_t* xpd = xpbf + (size_t)d*4096*1536;
  int q = lane;
  ushort_t xv = 0;
  if (wv == 3 && q < 48) xv = xpd[(size_t)0*1536 + (q >> 4)*512 + I0 + (q & 15)];

  float h_old = 0.0f;
  uint32* hb = hbuf + d*1024;
  __syncthreads();

  for (int t = 0; t < 4096; ++t) {
    // ---- phase X: acquire h_{t-1} (tag-validated, parity double-buffered) ----
    if (t > 0) {
      uint32 want = (uint32)(t - 1) & 0xffffu;
      uint32* slot = hb + ((t - 1) & 1)*512;
      uint32 v;
      while (((v = __hip_atomic_load(slot + tid, __ATOMIC_RELAXED,
                                     __HIP_MEMORY_SCOPE_AGENT)) & 0xffffu) != want)
        __builtin_amdgcn_s_sleep(1);
      h_bf[tid] = (ushort_t)(v >> 16);
      while (((v = __hip_atomic_load(slot + tid + 256, __ATOMIC_RELAXED,
                                     __HIP_MEMORY_SCOPE_AGENT)) & 0xffffu) != want)
        __builtin_amdgcn_s_sleep(1);
      h_bf[tid + 256] = (ushort_t)(v >> 16);
    }
    __syncthreads();
    // ---- phase A: matvec hp = W_hh · h via MFMA; wave 3 manages xp ----
    if (wv < 3) {
      f32x4 a0 = {0.f,0.f,0.f,0.f}, a1 = {0.f,0.f,0.f,0.f};
      #pragma unroll
      for (int kc = 0; kc < 16; kc += 2) {
        short8 hv0 = *(const short8*)(h_bf + kc*32 + quad*8);
        short8 hv1 = *(const short8*)(h_bf + (kc + 1)*32 + quad*8);
        a0 = __builtin_amdgcn_mfma_f32_16x16x32_bf16(wfrag[kc],     hv0, a0, 0, 0, 0);
        a1 = __builtin_amdgcn_mfma_f32_16x16x32_bf16(wfrag[kc + 1], hv1, a1, 0, 0, 0);
      }
      if (l15 == 0) {
        #pragma unroll
        for (int r = 0; r < 4; ++r) hp_lds[wv*16 + quad*4 + r] = a0[r] + a1[r];
      }
    } else {
      if (q < 48) {
        xpq[q] = xv;
        int tn = (t < 4095) ? (t + 1) : 4095;
        xv = xpd[(size_t)tn*1536 + (q >> 4)*512 + I0 + (q & 15)];
      }
    }
    __syncthreads();
    // ---- phase B: gates + publish (threads 0..15) ----
    if (tid < 16) {
      int c = tid;
      float xr = bf2f(xpq[c]), xz = bf2f(xpq[16 + c]), xn = bf2f(xpq[32 + c]);
      float hr = hp_lds[c]      + bhh_lds[c];
      float hz = hp_lds[16 + c] + bhh_lds[16 + c];
      float hn = hp_lds[32 + c] + bhh_lds[32 + c];
      float rg = 1.0f/(1.0f + __expf(-(xr + hr)));
      float zg = 1.0f/(1.0f + __expf(-(xz + hz)));
      float ng = tanhf(xn + rg*hn);
      float h  = (1.0f - zg)*ng + zg*h_old;
      h_old = h;
      int row = d ? (4095 - t) : t;
      outputs[(size_t)row*1024 + d*512 + I0 + c] = h;
      uint32 pub = (((uint32)f2bf(h)) << 16) | ((uint32)t & 0xffffu);
      __hip_atomic_store(hb + (t & 1)*512 + I0 + c, pub,
                         __ATOMIC_RELAXED, __HIP_MEMORY_SCOPE_AGENT);
    }
    __syncthreads();
  }
  if (tid < 16) {
    // hid = concat(hb_last, hf_last): d=1 -> [0..512), d=0 -> [512..1024)
    ws[WS_HID + (1 - d)*512 + I0 + tid] = h_old;
  }
}

// ============ K4a: scores[t] = outputs[t]·hid * scale  (+ zero lin) ============
__global__ __launch_bounds__(256) void k_scores(float* __restrict__ ws, float* __restrict__ outbase)
{
  if (blockIdx.x == 256) {
    float4 z = {0.f,0.f,0.f,0.f};
    ((float4*)outbase)[threadIdx.x] = z;   // zero lin[0..1024)
    return;
  }
  const float* outputs = outbase + ENERGY_OFF + OUTPUTS_OFF;
  const float* hid = ws + WS_HID;
  int tid = threadIdx.x, lane = tid & 63, wv = tid >> 6;
  float4 hv[4];
  #pragma unroll
  for (int c = 0; c < 4; ++c) hv[c] = *(const float4*)(hid + lane*16 + c*4);
  const float scale = 0.03125f;  // 1/sqrt(1024)
  for (int it = 0; it < 4; ++it) {
    int t = blockIdx.x*16 + wv*4 + it;
    const float4* o4 = (const float4*)(outputs + (size_t)t*1024 + lane*16);
    float p = 0.f;
    #pragma unroll
    for (int c = 0; c < 4; ++c) {
      float4 o = o4[c];
      p += o.x*hv[c].x + o.y*hv[c].y + o.z*hv[c].z + o.w*hv[c].w;
    }
    #pragma unroll
    for (int m = 1; m < 64; m <<= 1) p += __shfl_xor(p, m, 64);
    if (lane == 0) ws[WS_SCORES + t] = p*scale;
  }
}

// ============ K4b: softmax over 4096 scores (one block) ============
__global__ __launch_bounds__(1024) void k_softmax(float* __restrict__ ws)
{
  int tid = threadIdx.x, lane = tid & 63, wv = tid >> 6;
  __shared__ float sm[16];
  float4 s = *(const float4*)(ws + WS_SCORES + tid*4);
  float mx = fmaxf(fmaxf(s.x, s.y), fmaxf(s.z, s.w));
  #pragma unroll
  for (int m = 1; m < 64; m <<= 1) mx = fmaxf(mx, __shfl_xor(mx, m, 64));
  if (lane == 0) sm[wv] = mx;
  __syncthreads();
  float bm = sm[0];
  #pragma unroll
  for (int i = 1; i < 16; ++i) bm = fmaxf(bm, sm[i]);
  float e0 = __expf(s.x - bm), e1 = __expf(s.y - bm);
  float e2 = __expf(s.z - bm), e3 = __expf(s.w - bm);
  float ps = e0 + e1 + e2 + e3;
  #pragma unroll
  for (int m = 1; m < 64; m <<= 1) ps += __shfl_xor(ps, m, 64);
  __syncthreads();
  if (lane == 0) sm[wv] = ps;
  __syncthreads();
  float tot = 0.f;
  #pragma unroll
  for (int i = 0; i < 16; ++i) tot += sm[i];
  float inv = 1.0f/tot;
  float4 a = {e0*inv, e1*inv, e2*inv, e3*inv};
  *(float4*)(ws + WS_ATT + tid*4) = a;
}

// ============ K4c: lin[j] = sum_t att[t]*outputs[t][j] ============
__global__ __launch_bounds__(256) void k_lin(const float* __restrict__ ws, float* __restrict__ outbase)
{
  const float* outputs = outbase + ENERGY_OFF + OUTPUTS_OFF;
  const float* att = ws + WS_ATT;
  int jb = blockIdx.x & 3, tseg = blockIdx.x >> 2;
  int j = jb*256 + threadIdx.x;
  float acc = 0.f;
  int t0 = tseg*256;
  for (int t = t0; t < t0 + 256; ++t)
    acc += att[t]*outputs[(size_t)t*1024 + j];
  atomicAdd(outbase + j, acc);
}

// ============ K5: energy = diag(e), overwrites the whole scratch region ============
__global__ __launch_bounds__(256) void k_energy(const float* __restrict__ ws, float* __restrict__ outbase)
{
  float* energy = outbase + ENERGY_OFF;
  int t = blockIdx.x;
  float e = ws[WS_E + t];
  #pragma unroll
  for (int k = 0; k < 4; ++k) {
    int c4 = (threadIdx.x + k*256)*4;
    float4 v = {0.f,0.f,0.f,0.f};
    if (t >= c4 && t < c4 + 4) ((float*)&v)[t - c4] = e;
    *(float4*)(energy + (size_t)t*4096 + c4) = v;
  }
}

extern "C" void kernel_launch(void* const* d_in, const int* in_sizes, int n_in,
                              void* d_out, int out_size, void* d_ws, size_t ws_size,
                              hipStream_t stream) {
  const float* input  = (const float*)d_in[0];
  const float* query  = (const float*)d_in[1];
  const float* fc_w   = (const float*)d_in[2];
  const float* fc_b   = (const float*)d_in[3];
  const float* w_ih_f = (const float*)d_in[4];
  const float* w_hh_f = (const float*)d_in[5];
  const float* b_ih_f = (const float*)d_in[6];
  const float* b_hh_f = (const float*)d_in[7];
  const float* w_ih_b = (const float*)d_in[8];
  const float* w_hh_b = (const float*)d_in[9];
  const float* b_ih_b = (const float*)d_in[10];
  const float* b_hh_b = (const float*)d_in[11];
  float* out = (float*)d_out;
  float* ws  = (float*)d_ws;

  hipLaunchKernelGGL(k_prep,    dim3(2048),   dim3(256),  0, stream,
                     query, input, fc_w, fc_b, w_ih_f, w_ih_b, w_hh_f, w_hh_b, ws, out);
  hipLaunchKernelGGL(k_xp_gemm, dim3(64, 48), dim3(256),  0, stream, b_ih_f, b_ih_b, out);
  hipLaunchKernelGGL(k_gru,     dim3(64),     dim3(256),  0, stream, b_hh_f, b_hh_b, ws, out);
  hipLaunchKernelGGL(k_scores,  dim3(257),    dim3(256),  0, stream, ws, out);
  hipLaunchKernelGGL(k_softmax, dim3(1),      dim3(1024), 0, stream, ws);
  hipLaunchKernelGGL(k_lin,     dim3(64),     dim3(256),  0, stream, ws, out);
  hipLaunchKernelGGL(k_energy,  dim3(4096),   dim3(256),  0, stream, ws, out);
}